// Round 2
// baseline (225.803 us; speedup 1.0000x reference)
//
#include <hip/hip_runtime.h>

// SGConv: K=3 hops of \hat{A} x (symmetric gcn_norm w/ self-loops), then Linear.
// N=100000, E=1600000, F_in=32, F_out=64.
// Round 18: feature-split + XCD routing to make gather state L2-resident.
// R17 (16B loads) was ~neutral -> hop phase is line-touch-service bound, not
// per-wave-MLP bound. 6.4MB fp16 state > 4MB per-XCD L2 -> 60% of random
// touches hit L3. Split features into lo/hi 3.2MB halves; route blocks by
// blockIdx%8 (XCDs 0-3 -> lo, 4-7 -> hi) so each XCD's random set fits L2.
// hop3 unfused into routed half-gather + small streaming linear kernel.
// Also: per-node (e0,e1,dinv) packed in one int4; col segments padded to
// multiples of 4 so the unroll-4 col read is one aligned dwordx4.
// Keep: two-level radix build, per-wave replicated bin counters, fill3+
// prescale fusion, unroll-4 gather.

#define F_IN 32
#define F_OUT 64
#define SB_SHIFT 13                  // 8192 nodes per super-bucket
#define NSB_MAX 16
#define SUB_SHIFT 8                  // 256 nodes per sub-bucket
#define SUB (1 << SUB_SHIFT)
#define SPS 32                       // subs per super (8192/256)
#define EPB1 2048
#define EPB2 4096
#define SCAP 147456                  // super slab cap (mean 131072, sd ~347)
#define SUBCAP 6144                  // sub slab cap (mean 4096 + pad<=768)
#define BPS (SCAP / EPB2)            // 36 blocks per super in k_bin2

typedef float f4 __attribute__((ext_vector_type(4)));
typedef float f8 __attribute__((ext_vector_type(8)));
typedef _Float16 h8 __attribute__((ext_vector_type(8)));   // 16B
typedef int i2 __attribute__((ext_vector_type(2)));

// ---------- Level-1 bin: 13 supers; per-wave replicated hist/cursors ----------
__global__ __launch_bounds__(256) void k_bin1(const int* __restrict__ ei,
                                              int* __restrict__ scur,
                                              unsigned* __restrict__ b1, int E) {
    __shared__ unsigned stage[EPB1];          // 8 KB
    __shared__ unsigned char bidl[EPB1];      // 2 KB
    __shared__ int h4w[4][NSB_MAX];           // per-wave hist
    __shared__ int f4w[4][NSB_MAX];           // per-wave cursors
    __shared__ int lscanx[NSB_MAX], lbase[NSB_MAX];
    unsigned rec[EPB1 / 256];
    int      bk[EPB1 / 256];
    int tid = threadIdx.x;
    int wv = tid >> 6;
    int base = blockIdx.x * EPB1;
    int cnt = E - base; if (cnt > EPB1) cnt = EPB1;

    if (tid < 64) { h4w[tid >> 4][tid & 15] = 0; }
    __syncthreads();
#pragma unroll
    for (int k = 0; k < EPB1 / 256; ++k) {
        int i = base + k * 256 + tid;
        bk[k] = -1;
        if (i < E) {
            unsigned s = (unsigned)ei[i];
            unsigned d = (unsigned)ei[E + i];
            int b = d >> SB_SHIFT;
            rec[k] = (s << SB_SHIFT) | (d & ((1u << SB_SHIFT) - 1));
            bk[k] = b;
            atomicAdd(&h4w[wv][b], 1);
        }
    }
    __syncthreads();
    if (tid < 16) {
        int t0 = h4w[0][tid], t1 = h4w[1][tid], t2 = h4w[2][tid], t3 = h4w[3][tid];
        int tot = t0 + t1 + t2 + t3;
        int inc = tot;
#pragma unroll
        for (int off = 1; off < 16; off <<= 1) {
            int t = __shfl_up(inc, off);
            if (tid >= off) inc += t;
        }
        int excl = inc - tot;
        lscanx[tid] = excl;
        lbase[tid] = tot ? atomicAdd(&scur[tid], tot) : 0;
        f4w[0][tid] = excl;
        f4w[1][tid] = excl + t0;
        f4w[2][tid] = excl + t0 + t1;
        f4w[3][tid] = excl + t0 + t1 + t2;
    }
    __syncthreads();
#pragma unroll
    for (int k = 0; k < EPB1 / 256; ++k) {
        if (bk[k] >= 0) {
            int loc = atomicAdd(&f4w[wv][bk[k]], 1);
            stage[loc] = rec[k];
            bidl[loc] = (unsigned char)bk[k];
        }
    }
    __syncthreads();
    for (int k = 0; k < EPB1 / 256; ++k) {
        int idx = k * 256 + tid;
        if (idx < cnt) {
            int b = bidl[idx];
            b1[(size_t)b * SCAP + lbase[b] + (idx - lscanx[b])] = stage[idx];
        }
    }
}

// ---------- Level-2 bin: 32 subs per super; per-wave replicated ----------
__global__ __launch_bounds__(256) void k_bin2(const unsigned* __restrict__ b1,
                                              const int* __restrict__ scur,
                                              int* __restrict__ subcur,
                                              unsigned* __restrict__ b2) {
    int sb = blockIdx.x / BPS;
    int base = (blockIdx.x % BPS) * EPB2;
    int count = scur[sb];
    if (base >= count) return;
    int cnt = count - base; if (cnt > EPB2) cnt = EPB2;
    const unsigned* src = b1 + (size_t)sb * SCAP + base;

    __shared__ unsigned stage[EPB2];          // 16 KB
    __shared__ unsigned char bidl[EPB2];      // 4 KB
    __shared__ int h4w[4][SPS];
    __shared__ int f4w[4][SPS];
    __shared__ int lscanx[SPS], lbase[SPS];
    unsigned rec[EPB2 / 256];
    int tid = threadIdx.x;
    int wv = tid >> 6;
    if (tid < 128) h4w[tid >> 5][tid & 31] = 0;
    __syncthreads();
#pragma unroll
    for (int k = 0; k < EPB2 / 256; ++k) {
        int i = k * 256 + tid;
        rec[k] = 0xFFFFFFFFu;
        if (i < cnt) {
            unsigned r = src[i];
            rec[k] = r;
            atomicAdd(&h4w[wv][(r >> SUB_SHIFT) & (SPS - 1)], 1);
        }
    }
    __syncthreads();
    if (tid < 32) {
        int t0 = h4w[0][tid], t1 = h4w[1][tid], t2 = h4w[2][tid], t3 = h4w[3][tid];
        int tot = t0 + t1 + t2 + t3;
        int inc = tot;
#pragma unroll
        for (int off = 1; off < 32; off <<= 1) {
            int t = __shfl_up(inc, off);
            if (tid >= off) inc += t;
        }
        int excl = inc - tot;
        lscanx[tid] = excl;
        lbase[tid] = tot ? atomicAdd(&subcur[sb * SPS + tid], tot) : 0;
        f4w[0][tid] = excl;
        f4w[1][tid] = excl + t0;
        f4w[2][tid] = excl + t0 + t1;
        f4w[3][tid] = excl + t0 + t1 + t2;
    }
    __syncthreads();
#pragma unroll
    for (int k = 0; k < EPB2 / 256; ++k) {
        if (rec[k] != 0xFFFFFFFFu) {
            int b = (rec[k] >> SUB_SHIFT) & (SPS - 1);
            int loc = atomicAdd(&f4w[wv][b], 1);
            stage[loc] = rec[k];
            bidl[loc] = (unsigned char)b;
        }
    }
    __syncthreads();
    for (int k = 0; k < EPB2 / 256; ++k) {
        int idx = k * 256 + tid;
        if (idx < cnt) {
            unsigned r = stage[idx];
            int b = bidl[idx];
            unsigned packed = ((r >> SB_SHIFT) << SUB_SHIFT) | (r & (SUB - 1));
            b2[(size_t)(sb * SPS + b) * SUBCAP + lbase[b] + (idx - lscanx[b])] = packed;
        }
    }
}

// ---------- fill3: counting sort per 256-node sub; padded col segments;
// ---------- packed node record; fused prescale into lo/hi half arrays ----------
__global__ __launch_bounds__(256) void k_fill3(const unsigned* __restrict__ b2,
                                               const int* __restrict__ subcur,
                                               const f4* __restrict__ x,
                                               int4* __restrict__ nrec,
                                               int* __restrict__ col,
                                               h8* __restrict__ g_lo,
                                               h8* __restrict__ g_hi, int N) {
    __shared__ unsigned stage[SUBCAP];        // 24 KB
    __shared__ int h[SUB];
    __shared__ float dl[SUB];
    __shared__ int wsum[4];
    int tid = threadIdx.x;
    int g = blockIdx.x;
    int count = subcur[g];
    int sbase = g * SUBCAP;
    int n0 = g << SUB_SHIFT;

    h[tid] = 0;
    for (int e = tid; e < count; e += 256) stage[e] = b2[(size_t)sbase + e];
    __syncthreads();
    for (int e = tid; e < count; e += 256) atomicAdd(&h[stage[e] & (SUB - 1)], 1);
    __syncthreads();

    int deg = h[tid];
    int pdeg = (deg + 3) & ~3;          // pad each node's segment to x4
    int lane = tid & 63, wid = tid >> 6;
    int inc = pdeg;
#pragma unroll
    for (int off = 1; off < 64; off <<= 1) {
        int t = __shfl_up(inc, off);
        if (lane >= off) inc += t;
    }
    if (lane == 63) wsum[wid] = inc;
    __syncthreads();
    if (wid == 0) {
        int v = (lane < 4) ? wsum[lane] : 0;
#pragma unroll
        for (int off = 1; off < 4; off <<= 1) {
            int t = __shfl_up(v, off);
            if (lane >= off) v += t;
        }
        if (lane < 4) wsum[lane] = v;
    }
    __syncthreads();
    int incl = inc + (wid ? wsum[wid - 1] : 0);
    int exclp = incl - pdeg;

    int node = n0 + tid;
    float di = rsqrtf(1.0f + (float)deg);
    dl[tid] = di;
    if (node < N) {
        int e0a = sbase + exclp;
        nrec[node] = make_int4(e0a, e0a + deg, __float_as_int(di), 0);
    }
    h[tid] = exclp;
    __syncthreads();

    for (int e = tid; e < count; e += 256) {
        unsigned r = stage[e];
        int slot = sbase + atomicAdd(&h[r & (SUB - 1)], 1);
        col[slot] = (int)(r >> SUB_SHIFT);
    }

    // fused prescale: g = fp16(dinv .* x) split into lo/hi 16-feature halves
    for (int idx = tid; idx < SUB * 4; idx += 256) {
        int nl = idx >> 2;
        int q = idx & 3;
        int node2 = n0 + nl;
        if (node2 < N) {
            int gi = node2 * 8 + q * 2;
            f4 vlo = dl[nl] * x[gi];
            f4 vhi = dl[nl] * x[gi + 1];
            f8 v = __builtin_shufflevector(vlo, vhi, 0, 1, 2, 3, 4, 5, 6, 7);
            h8 hv = __builtin_convertvector(v, h8);
            if (q < 2) g_lo[(size_t)node2 * 2 + q] = hv;
            else       g_hi[(size_t)node2 * 2 + (q - 2)] = hv;
        }
    }
}

// ---------- XCD-routed half-hop: blocks on XCDs 0-3 process the lo half,
// ---------- 4-7 the hi half. 2 lanes/node x 16B. isfinal: scale di not di^2.
__global__ __launch_bounds__(256) void k_hop_half(const int4* __restrict__ nrec,
                                                  const int* __restrict__ col,
                                                  const h8* __restrict__ gin_lo,
                                                  const h8* __restrict__ gin_hi,
                                                  h8* __restrict__ gout_lo,
                                                  h8* __restrict__ gout_hi,
                                                  int N, int hblocks, int isfinal) {
    int bid = blockIdx.x;
    int grp = bid & 7;                       // assumed XCD id (perf-only)
    int lblk = (bid >> 3) * 4 + (grp & 3);
    if (lblk >= hblocks) return;
    const h8* __restrict__ gin  = (grp < 4) ? gin_lo  : gin_hi;
    h8*       __restrict__ gout = (grp < 4) ? gout_lo : gout_hi;
    int t = lblk * 256 + threadIdx.x;
    int n = t >> 1;
    if (n >= N) return;
    int q = t & 1;
    int4 r = nrec[n];
    int e0 = r.x, e1 = r.y;
    float di = __int_as_float(r.z);
    f8 a0 = __builtin_convertvector(gin[(size_t)n * 2 + q], f8);   // self-loop
    f8 a1 = {0.f, 0.f, 0.f, 0.f, 0.f, 0.f, 0.f, 0.f};
    int e = e0;
    for (; e + 3 < e1; e += 4) {
        int4 c4 = *(const int4*)(col + e);   // 16B-aligned: e0 % 4 == 0
        h8 h0 = gin[(size_t)c4.x * 2 + q];
        h8 h1 = gin[(size_t)c4.y * 2 + q];
        h8 h2 = gin[(size_t)c4.z * 2 + q];
        h8 h3 = gin[(size_t)c4.w * 2 + q];
        a0 += __builtin_convertvector(h0, f8);
        a1 += __builtin_convertvector(h1, f8);
        a0 += __builtin_convertvector(h2, f8);
        a1 += __builtin_convertvector(h3, f8);
    }
    for (; e < e1; ++e) a0 += __builtin_convertvector(gin[(size_t)col[e] * 2 + q], f8);
    float sc = isfinal ? di : di * di;
    f8 rr = sc * (a0 + a1);
    gout[(size_t)n * 2 + q] = __builtin_convertvector(rr, h8);
}

// ---------- Linear: streaming read of hD halves, conflict-free GEMM epilogue ----------
__global__ __launch_bounds__(256) void k_linear(const h8* __restrict__ lo,
                                                const h8* __restrict__ hi,
                                                const float* __restrict__ W,
                                                const float* __restrict__ bias,
                                                float* __restrict__ out, int N) {
    __shared__ float Wl[F_OUT][F_IN + 1];   // 8.4 KB
    __shared__ float hl[64][F_IN + 1];      // 8.4 KB
    int tid = threadIdx.x;
    for (int idx = tid; idx < F_OUT * F_IN; idx += 256)
        Wl[idx >> 5][idx & 31] = W[idx];

    int nbase = blockIdx.x * 64;
    {
        int nl = tid >> 2;                  // 0..63
        int c = tid & 3;                    // 16B chunk: 0,1=lo 2,3=hi
        int n = nbase + nl;
        if (n < N) {
            h8 v = (c < 2) ? lo[(size_t)n * 2 + c] : hi[(size_t)n * 2 + (c - 2)];
            f8 f = __builtin_convertvector(v, f8);
#pragma unroll
            for (int i = 0; i < 8; ++i) hl[nl][c * 8 + i] = f[i];
        }
    }
    __syncthreads();
    int o = tid & 63;
    float wreg[F_IN];
#pragma unroll
    for (int f = 0; f < F_IN; ++f) wreg[f] = Wl[o][f];
    float bv = bias[o];
    int nchunk = tid >> 6;  // 0..3
#pragma unroll
    for (int p = 0; p < 16; ++p) {
        int nloc = p * 4 + nchunk;
        int nn = nbase + nloc;
        if (nn < N) {
            float acc = bv;
#pragma unroll
            for (int f = 0; f < F_IN; ++f) acc += hl[nloc][f] * wreg[f];
            out[(size_t)nn * F_OUT + o] = acc;
        }
    }
}

extern "C" void kernel_launch(void* const* d_in, const int* in_sizes, int n_in,
                              void* d_out, int out_size, void* d_ws, size_t ws_size,
                              hipStream_t stream) {
    const float* x  = (const float*)d_in[0];
    const int*   ei = (const int*)d_in[1];   // [2,E] int32: src row then dst row
    const float* W  = (const float*)d_in[2];
    const float* b  = (const float*)d_in[3];
    float* out = (float*)d_out;

    const int N = in_sizes[0] / F_IN;
    const int E = in_sizes[1] / 2;
    const int NSB  = (N + (1 << SB_SHIFT) - 1) >> SB_SHIFT;   // 13
    const int NSUB = (N + SUB - 1) >> SUB_SHIFT;              // 391

    // ws: scur(16) | subcur(16*32) | nrec(16B*N) | b1 | b2 | col | halves x4
    int* scur   = (int*)d_ws;
    int* subcur = scur + NSB_MAX;
    int4* nrec  = (int4*)(((uintptr_t)(subcur + NSB_MAX * SPS) + 255) & ~(uintptr_t)255);
    unsigned* b1 = (unsigned*)(((uintptr_t)(nrec + N) + 255) & ~(uintptr_t)255);
    unsigned* b2 = b1 + (size_t)NSB_MAX * SCAP;
    int* col     = (int*)(b2 + (size_t)NSB_MAX * SPS * SUBCAP);
    _Float16* hbase = (_Float16*)(((uintptr_t)(col + (size_t)NSB_MAX * SPS * SUBCAP) + 255)
                                  & ~(uintptr_t)255);
    const size_t HALF = (size_t)N * (F_IN / 2);   // halfs per half-array
    _Float16* hAlo = hbase;
    _Float16* hAhi = hAlo + HALF;
    _Float16* hBlo = hAhi + HALF;
    _Float16* hBhi = hBlo + HALF;

    const int B = 256;
    dim3 blk(B);

    hipMemsetAsync(scur, 0, (NSB_MAX + NSB_MAX * SPS) * sizeof(int), stream);

    // two-level radix partition
    k_bin1<<<dim3((E + EPB1 - 1) / EPB1), blk, 0, stream>>>(ei, scur, b1, E);
    k_bin2<<<dim3(NSB * BPS), blk, 0, stream>>>(b1, scur, subcur, b2);

    // per-sub counting sort + fused prescale (-> hA lo/hi)
    k_fill3<<<dim3(NSUB), blk, 0, stream>>>(b2, subcur, (const f4*)x,
                                            nrec, col, (h8*)hAlo, (h8*)hAhi, N);

    // hops, XCD-routed halves: A->B, B->A, A->B(final scale)
    const int HB = (N * 2 + B - 1) / B;          // 782 blocks per half
    dim3 gHop(8 * ((HB + 3) / 4));               // 1568
    k_hop_half<<<gHop, blk, 0, stream>>>(nrec, col, (const h8*)hAlo, (const h8*)hAhi,
                                         (h8*)hBlo, (h8*)hBhi, N, HB, 0);
    k_hop_half<<<gHop, blk, 0, stream>>>(nrec, col, (const h8*)hBlo, (const h8*)hBhi,
                                         (h8*)hAlo, (h8*)hAhi, N, HB, 0);
    k_hop_half<<<gHop, blk, 0, stream>>>(nrec, col, (const h8*)hAlo, (const h8*)hAhi,
                                         (h8*)hBlo, (h8*)hBhi, N, HB, 1);

    // linear: hB (lo,hi) -> out
    k_linear<<<dim3((N + 63) / 64), blk, 0, stream>>>((const h8*)hBlo, (const h8*)hBhi,
                                                      W, b, out, N);
}

// Round 3
// 206.738 us; speedup vs baseline: 1.0922x; 1.0922x over previous
//
#include <hip/hip_runtime.h>

// SGConv: K=3 hops of \hat{A} x (symmetric gcn_norm w/ self-loops), then Linear.
// N=100000, E=1600000, F_in=32, F_out=64.
// Round 19: revert R18's feature split (doubled line touches -> +12.7%).
// Back to R17 full-row layout (1 line/edge, 100% bytes used) plus:
//  (a) depth-1 software pipeline of col dwordx4 loads (next batch's col
//      issued before waiting on current gathers) - removes ~200cy col
//      latency from each gather batch chain;
//  (b) nontemporal hints on STREAMING accesses only (col/nrec/x loads,
//      gout/g0/out stores) so the 6.4MB gin state keeps more of the
//      4MB/XCD L2 (gather loads stay temporal - opposite polarity of R15);
//  (c) keep R18's padded col segments (aligned dwordx4) and packed 16B
//      nrec (e0,e1,dinv) record.
// Keep: two-level radix build, per-wave replicated bin counters, fill3+
// prescale fusion, unroll-4 gathers, fused hop3+linear conflict-free epilogue.

#define F_IN 32
#define F_OUT 64
#define SB_SHIFT 13                  // 8192 nodes per super-bucket
#define NSB_MAX 16
#define SUB_SHIFT 8                  // 256 nodes per sub-bucket
#define SUB (1 << SUB_SHIFT)
#define SPS 32                       // subs per super (8192/256)
#define EPB1 2048
#define EPB2 4096
#define SCAP 147456                  // super slab cap (mean 131072, sd ~347)
#define SUBCAP 6144                  // sub slab cap (mean 4096 + pad<=768)
#define BPS (SCAP / EPB2)            // 36 blocks per super in k_bin2

typedef float f4 __attribute__((ext_vector_type(4)));
typedef float f8 __attribute__((ext_vector_type(8)));
typedef _Float16 h8 __attribute__((ext_vector_type(8)));   // 16B
typedef int i4 __attribute__((ext_vector_type(4)));

// ---------- Level-1 bin: 13 supers; per-wave replicated hist/cursors ----------
__global__ __launch_bounds__(256) void k_bin1(const int* __restrict__ ei,
                                              int* __restrict__ scur,
                                              unsigned* __restrict__ b1, int E) {
    __shared__ unsigned stage[EPB1];          // 8 KB
    __shared__ unsigned char bidl[EPB1];      // 2 KB
    __shared__ int h4w[4][NSB_MAX];           // per-wave hist
    __shared__ int f4w[4][NSB_MAX];           // per-wave cursors
    __shared__ int lscanx[NSB_MAX], lbase[NSB_MAX];
    unsigned rec[EPB1 / 256];
    int      bk[EPB1 / 256];
    int tid = threadIdx.x;
    int wv = tid >> 6;
    int base = blockIdx.x * EPB1;
    int cnt = E - base; if (cnt > EPB1) cnt = EPB1;

    if (tid < 64) { h4w[tid >> 4][tid & 15] = 0; }
    __syncthreads();
#pragma unroll
    for (int k = 0; k < EPB1 / 256; ++k) {
        int i = base + k * 256 + tid;
        bk[k] = -1;
        if (i < E) {
            unsigned s = (unsigned)ei[i];
            unsigned d = (unsigned)ei[E + i];
            int b = d >> SB_SHIFT;
            rec[k] = (s << SB_SHIFT) | (d & ((1u << SB_SHIFT) - 1));
            bk[k] = b;
            atomicAdd(&h4w[wv][b], 1);
        }
    }
    __syncthreads();
    if (tid < 16) {
        int t0 = h4w[0][tid], t1 = h4w[1][tid], t2 = h4w[2][tid], t3 = h4w[3][tid];
        int tot = t0 + t1 + t2 + t3;
        int inc = tot;
#pragma unroll
        for (int off = 1; off < 16; off <<= 1) {
            int t = __shfl_up(inc, off);
            if (tid >= off) inc += t;
        }
        int excl = inc - tot;
        lscanx[tid] = excl;
        lbase[tid] = tot ? atomicAdd(&scur[tid], tot) : 0;
        f4w[0][tid] = excl;
        f4w[1][tid] = excl + t0;
        f4w[2][tid] = excl + t0 + t1;
        f4w[3][tid] = excl + t0 + t1 + t2;
    }
    __syncthreads();
#pragma unroll
    for (int k = 0; k < EPB1 / 256; ++k) {
        if (bk[k] >= 0) {
            int loc = atomicAdd(&f4w[wv][bk[k]], 1);
            stage[loc] = rec[k];
            bidl[loc] = (unsigned char)bk[k];
        }
    }
    __syncthreads();
    for (int k = 0; k < EPB1 / 256; ++k) {
        int idx = k * 256 + tid;
        if (idx < cnt) {
            int b = bidl[idx];
            b1[(size_t)b * SCAP + lbase[b] + (idx - lscanx[b])] = stage[idx];
        }
    }
}

// ---------- Level-2 bin: 32 subs per super; per-wave replicated ----------
__global__ __launch_bounds__(256) void k_bin2(const unsigned* __restrict__ b1,
                                              const int* __restrict__ scur,
                                              int* __restrict__ subcur,
                                              unsigned* __restrict__ b2) {
    int sb = blockIdx.x / BPS;
    int base = (blockIdx.x % BPS) * EPB2;
    int count = scur[sb];
    if (base >= count) return;
    int cnt = count - base; if (cnt > EPB2) cnt = EPB2;
    const unsigned* src = b1 + (size_t)sb * SCAP + base;

    __shared__ unsigned stage[EPB2];          // 16 KB
    __shared__ unsigned char bidl[EPB2];      // 4 KB
    __shared__ int h4w[4][SPS];
    __shared__ int f4w[4][SPS];
    __shared__ int lscanx[SPS], lbase[SPS];
    unsigned rec[EPB2 / 256];
    int tid = threadIdx.x;
    int wv = tid >> 6;
    if (tid < 128) h4w[tid >> 5][tid & 31] = 0;
    __syncthreads();
#pragma unroll
    for (int k = 0; k < EPB2 / 256; ++k) {
        int i = k * 256 + tid;
        rec[k] = 0xFFFFFFFFu;
        if (i < cnt) {
            unsigned r = src[i];
            rec[k] = r;
            atomicAdd(&h4w[wv][(r >> SUB_SHIFT) & (SPS - 1)], 1);
        }
    }
    __syncthreads();
    if (tid < 32) {
        int t0 = h4w[0][tid], t1 = h4w[1][tid], t2 = h4w[2][tid], t3 = h4w[3][tid];
        int tot = t0 + t1 + t2 + t3;
        int inc = tot;
#pragma unroll
        for (int off = 1; off < 32; off <<= 1) {
            int t = __shfl_up(inc, off);
            if (tid >= off) inc += t;
        }
        int excl = inc - tot;
        lscanx[tid] = excl;
        lbase[tid] = tot ? atomicAdd(&subcur[sb * SPS + tid], tot) : 0;
        f4w[0][tid] = excl;
        f4w[1][tid] = excl + t0;
        f4w[2][tid] = excl + t0 + t1;
        f4w[3][tid] = excl + t0 + t1 + t2;
    }
    __syncthreads();
#pragma unroll
    for (int k = 0; k < EPB2 / 256; ++k) {
        if (rec[k] != 0xFFFFFFFFu) {
            int b = (rec[k] >> SUB_SHIFT) & (SPS - 1);
            int loc = atomicAdd(&f4w[wv][b], 1);
            stage[loc] = rec[k];
            bidl[loc] = (unsigned char)b;
        }
    }
    __syncthreads();
    for (int k = 0; k < EPB2 / 256; ++k) {
        int idx = k * 256 + tid;
        if (idx < cnt) {
            unsigned r = stage[idx];
            int b = bidl[idx];
            unsigned packed = ((r >> SB_SHIFT) << SUB_SHIFT) | (r & (SUB - 1));
            b2[(size_t)(sb * SPS + b) * SUBCAP + lbase[b] + (idx - lscanx[b])] = packed;
        }
    }
}

// ---------- fill3: counting sort per 256-node sub; padded col segments;
// ---------- packed 16B node record; fused full-row prescale ----------
__global__ __launch_bounds__(256) void k_fill3(const unsigned* __restrict__ b2,
                                               const int* __restrict__ subcur,
                                               const f4* __restrict__ x,
                                               i4* __restrict__ nrec,
                                               int* __restrict__ col,
                                               h8* __restrict__ g0, int N) {
    __shared__ unsigned stage[SUBCAP];        // 24 KB
    __shared__ int h[SUB];
    __shared__ float dl[SUB];
    __shared__ int wsum[4];
    int tid = threadIdx.x;
    int g = blockIdx.x;
    int count = subcur[g];
    int sbase = g * SUBCAP;
    int n0 = g << SUB_SHIFT;

    h[tid] = 0;
    for (int e = tid; e < count; e += 256) stage[e] = b2[(size_t)sbase + e];
    __syncthreads();
    for (int e = tid; e < count; e += 256) atomicAdd(&h[stage[e] & (SUB - 1)], 1);
    __syncthreads();

    int deg = h[tid];
    int pdeg = (deg + 3) & ~3;          // pad each node's segment to x4
    int lane = tid & 63, wid = tid >> 6;
    int inc = pdeg;
#pragma unroll
    for (int off = 1; off < 64; off <<= 1) {
        int t = __shfl_up(inc, off);
        if (lane >= off) inc += t;
    }
    if (lane == 63) wsum[wid] = inc;
    __syncthreads();
    if (wid == 0) {
        int v = (lane < 4) ? wsum[lane] : 0;
#pragma unroll
        for (int off = 1; off < 4; off <<= 1) {
            int t = __shfl_up(v, off);
            if (lane >= off) v += t;
        }
        if (lane < 4) wsum[lane] = v;
    }
    __syncthreads();
    int incl = inc + (wid ? wsum[wid - 1] : 0);
    int exclp = incl - pdeg;

    int node = n0 + tid;
    float di = rsqrtf(1.0f + (float)deg);
    dl[tid] = di;
    if (node < N) {
        int e0a = sbase + exclp;
        nrec[node] = (i4){e0a, e0a + deg, (int)__float_as_int(di), 0};
    }
    h[tid] = exclp;
    __syncthreads();

    for (int e = tid; e < count; e += 256) {
        unsigned r = stage[e];
        int slot = sbase + atomicAdd(&h[r & (SUB - 1)], 1);
        col[slot] = (int)(r >> SUB_SHIFT);
    }

    // fused prescale: g0 = fp16(dinv .* x), full 64B rows, nt stores
    for (int idx = tid; idx < SUB * 4; idx += 256) {
        int nl = idx >> 2;
        int q = idx & 3;
        int node2 = n0 + nl;
        if (node2 < N) {
            int gi = node2 * 8 + q * 2;
            f4 vlo = dl[nl] * __builtin_nontemporal_load(&x[gi]);
            f4 vhi = dl[nl] * __builtin_nontemporal_load(&x[gi + 1]);
            f8 v = __builtin_shufflevector(vlo, vhi, 0, 1, 2, 3, 4, 5, 6, 7);
            __builtin_nontemporal_store(__builtin_convertvector(v, h8),
                                        &g0[(size_t)node2 * 4 + q]);
        }
    }
}

// ---------- Mid hop (hops 1,2): 4 lanes/row, 16B gathers,
// ---------- depth-1 col pipeline, nt on streaming accesses ----------
__global__ __launch_bounds__(256) void k_hop_gather(const i4* __restrict__ nrec,
                                                    const int* __restrict__ col,
                                                    const h8* __restrict__ gin,
                                                    h8* __restrict__ gout, int N) {
    int t = blockIdx.x * blockDim.x + threadIdx.x;
    int n = t >> 2;
    if (n >= N) return;
    int q = t & 3;
    i4 r = __builtin_nontemporal_load(&nrec[n]);
    int e0 = r.x, e1 = r.y;
    float di = __int_as_float(r.z);
    f8 a0 = __builtin_convertvector(gin[(size_t)n * 4 + q], f8);  // self-loop
    f8 a1 = {0.f, 0.f, 0.f, 0.f, 0.f, 0.f, 0.f, 0.f};
    int e = e0;
    if (e + 3 < e1) {
        i4 c4 = __builtin_nontemporal_load((const i4*)(col + e));  // aligned x4
        for (;;) {
            int en = e + 4;
            bool more = (en + 3 < e1);
            i4 cn;
            if (more) cn = __builtin_nontemporal_load((const i4*)(col + en));
            h8 h0 = gin[(size_t)c4.x * 4 + q];
            h8 h1 = gin[(size_t)c4.y * 4 + q];
            h8 h2 = gin[(size_t)c4.z * 4 + q];
            h8 h3 = gin[(size_t)c4.w * 4 + q];
            a0 += __builtin_convertvector(h0, f8);
            a1 += __builtin_convertvector(h1, f8);
            a0 += __builtin_convertvector(h2, f8);
            a1 += __builtin_convertvector(h3, f8);
            e = en;
            if (!more) break;
            c4 = cn;
        }
    }
    for (; e < e1; ++e) a0 += __builtin_convertvector(gin[(size_t)col[e] * 4 + q], f8);
    float sc = di * di;
    f8 rr = sc * (a0 + a1);
    __builtin_nontemporal_store(__builtin_convertvector(rr, h8),
                                &gout[(size_t)n * 4 + q]);
}

// ---------- Final hop FUSED with linear; conflict-free epilogue ----------
// Block = 256 thr = 64 nodes x 4 lanes (gather), then 16 passes of 4 nodes x 64 o.
__global__ __launch_bounds__(256) void k_hop3_linear(const i4* __restrict__ nrec,
                                                     const int* __restrict__ col,
                                                     const h8* __restrict__ gin,
                                                     const float* __restrict__ W,
                                                     const float* __restrict__ bias,
                                                     float* __restrict__ out, int N) {
    __shared__ float Wl[F_OUT][F_IN + 1];   // 8.4 KB
    __shared__ float hl[64][F_IN + 1];      // 8.4 KB
    int tid = threadIdx.x;
    for (int idx = tid; idx < F_OUT * F_IN; idx += 256)
        Wl[idx >> 5][idx & 31] = W[idx];

    int nl = tid >> 2;                 // 0..63 local node
    int q = tid & 3;
    int nbase = blockIdx.x * 64;
    int n = nbase + nl;
    if (n < N) {
        i4 r = __builtin_nontemporal_load(&nrec[n]);
        int e0 = r.x, e1 = r.y;
        float di = __int_as_float(r.z);
        f8 a0 = __builtin_convertvector(gin[(size_t)n * 4 + q], f8);
        f8 a1 = {0.f, 0.f, 0.f, 0.f, 0.f, 0.f, 0.f, 0.f};
        int e = e0;
        if (e + 3 < e1) {
            i4 c4 = __builtin_nontemporal_load((const i4*)(col + e));
            for (;;) {
                int en = e + 4;
                bool more = (en + 3 < e1);
                i4 cn;
                if (more) cn = __builtin_nontemporal_load((const i4*)(col + en));
                h8 h0 = gin[(size_t)c4.x * 4 + q];
                h8 h1 = gin[(size_t)c4.y * 4 + q];
                h8 h2 = gin[(size_t)c4.z * 4 + q];
                h8 h3 = gin[(size_t)c4.w * 4 + q];
                a0 += __builtin_convertvector(h0, f8);
                a1 += __builtin_convertvector(h1, f8);
                a0 += __builtin_convertvector(h2, f8);
                a1 += __builtin_convertvector(h3, f8);
                e = en;
                if (!more) break;
                c4 = cn;
            }
        }
        for (; e < e1; ++e) a0 += __builtin_convertvector(gin[(size_t)col[e] * 4 + q], f8);
        float di2 = di;
        f8 rr = di2 * (a0 + a1);
#pragma unroll
        for (int i = 0; i < 8; ++i) hl[nl][q * 8 + i] = rr[i];
    }
    __syncthreads();
    // W row -> registers, conflict-free: lanes o=0..63 read Wl[o][f], bank (o+f)%32
    int o = tid & 63;
    float wreg[F_IN];
#pragma unroll
    for (int f = 0; f < F_IN; ++f) wreg[f] = Wl[o][f];
    float bv = bias[o];
    // 16 passes x 4 nodes: node index wave-uniform -> hl reads broadcast
    int nchunk = tid >> 6;  // 0..3
#pragma unroll
    for (int p = 0; p < 16; ++p) {
        int nloc = p * 4 + nchunk;
        int nn = nbase + nloc;
        if (nn < N) {
            float acc = bv;
#pragma unroll
            for (int f = 0; f < F_IN; ++f) acc += hl[nloc][f] * wreg[f];
            __builtin_nontemporal_store(acc, &out[(size_t)nn * F_OUT + o]);
        }
    }
}

extern "C" void kernel_launch(void* const* d_in, const int* in_sizes, int n_in,
                              void* d_out, int out_size, void* d_ws, size_t ws_size,
                              hipStream_t stream) {
    const float* x  = (const float*)d_in[0];
    const int*   ei = (const int*)d_in[1];   // [2,E] int32: src row then dst row
    const float* W  = (const float*)d_in[2];
    const float* b  = (const float*)d_in[3];
    float* out = (float*)d_out;

    const int N = in_sizes[0] / F_IN;
    const int E = in_sizes[1] / 2;
    const int NSB  = (N + (1 << SB_SHIFT) - 1) >> SB_SHIFT;   // 13
    const int NSUB = (N + SUB - 1) >> SUB_SHIFT;              // 391

    // ws: scur(16) | subcur(16*32) | nrec(16B*N) | b1 | b2 | col | hA hB
    int* scur   = (int*)d_ws;
    int* subcur = scur + NSB_MAX;
    i4* nrec    = (i4*)(((uintptr_t)(subcur + NSB_MAX * SPS) + 255) & ~(uintptr_t)255);
    unsigned* b1 = (unsigned*)(((uintptr_t)(nrec + N) + 255) & ~(uintptr_t)255);
    unsigned* b2 = b1 + (size_t)NSB_MAX * SCAP;
    int* col     = (int*)(b2 + (size_t)NSB_MAX * SPS * SUBCAP);
    _Float16* hA = (_Float16*)(((uintptr_t)(col + (size_t)NSB_MAX * SPS * SUBCAP) + 255)
                               & ~(uintptr_t)255);
    _Float16* hB = hA + (size_t)N * F_IN;

    const int B = 256;
    dim3 blk(B);

    hipMemsetAsync(scur, 0, (NSB_MAX + NSB_MAX * SPS) * sizeof(int), stream);

    // two-level radix partition
    k_bin1<<<dim3((E + EPB1 - 1) / EPB1), blk, 0, stream>>>(ei, scur, b1, E);
    k_bin2<<<dim3(NSB * BPS), blk, 0, stream>>>(b1, scur, subcur, b2);

    // per-sub counting sort + fused prescale (g0 -> hA)
    k_fill3<<<dim3(NSUB), blk, 0, stream>>>(b2, subcur, (const f4*)x,
                                            nrec, col, (h8*)hA, N);

    // hops 1,2 (ping-pong): hA -> hB -> hA
    dim3 gHop(((size_t)N * 4 + B - 1) / B);
    k_hop_gather<<<gHop, blk, 0, stream>>>(nrec, col, (const h8*)hA, (h8*)hB, N);
    k_hop_gather<<<gHop, blk, 0, stream>>>(nrec, col, (const h8*)hB, (h8*)hA, N);

    // hop 3 fused with linear: hA -> out
    k_hop3_linear<<<dim3((N + 63) / 64), blk, 0, stream>>>(nrec, col,
                                                           (const h8*)hA, W, b, out, N);
}